// Round 3
// baseline (679.552 us; speedup 1.0000x reference)
//
#include <hip/hip_runtime.h>

#define E_NUM 12000
#define D_DIM 6272
#define H_DIM 256
#define M1 (2 * E_NUM)  // 24000

typedef __attribute__((ext_vector_type(8))) short short8;
typedef __attribute__((ext_vector_type(8))) __bf16 bf16x8;
typedef __attribute__((ext_vector_type(4))) float f32x4;

__device__ __forceinline__ short f2bf(float f) {
  union { float f; unsigned u; } v; v.f = f;
  unsigned r = (v.u + 0x7FFFu + ((v.u >> 16) & 1u)) >> 16;
  return (short)r;
}

__device__ __forceinline__ float silu_f(float x) {
  return x / (1.0f + __expf(-x));
}

__device__ __forceinline__ bf16x8 ld_frag(const short* p) {
  return __builtin_bit_cast(bf16x8, *(const short8*)p);
}

// -------------------- transpose + fp32->bf16 convert --------------------
__global__ void transpose_cvt(const float* __restrict__ src, short* __restrict__ dst,
                              int R, int C) {
  __shared__ float tile[32][33];
  const int bx = blockIdx.x;  // over C/32
  const int by = blockIdx.y;  // over R/32
  const int t = threadIdx.x;
  const int ci = t & 31;
  const int r0 = t >> 5;
#pragma unroll
  for (int i = 0; i < 4; ++i) {
    int ri = r0 + i * 8;
    tile[ri][ci] = src[(size_t)(by * 32 + ri) * C + bx * 32 + ci];
  }
  __syncthreads();
#pragma unroll
  for (int i = 0; i < 4; ++i) {
    int orow = r0 + i * 8;
    dst[(size_t)(bx * 32 + orow) * R + by * 32 + ci] = f2bf(tile[ci][orow]);
  }
}

// -------------------- GEMM1 v3: BM=64, BK=128, B direct-from-L2, A reg-staged+swz LDS ----
// x = concat(node_embed, ori) [24000][6272] fp32, W1T [256][6272] bf16 (ws)
// hg [24000][256] bf16 out
// 512 threads = 8 waves (2 M-halves x 4 N-quarters). 49 stages of BK=128 (4 ksteps).
#define G1_STAGES 49
__launch_bounds__(512, 2)
__global__ void gemm1_kernel(const float* __restrict__ node_embed,
                             const float* __restrict__ ori,
                             const float* __restrict__ x_edge_c,
                             const short* __restrict__ W1T,
                             const float* __restrict__ b1,
                             short* __restrict__ hg) {
  // A tile: [64 rows][128 shorts] per buffer, XOR-swizzled: 16B-chunk c of row r
  // stored at chunk position c ^ (r&7). Reads 2-way (free), writes 4-way.
  __shared__ __align__(16) short Als[2][64 * 128];  // 32 KB total

  const int t = threadIdx.x;
  const int wave = t >> 6;
  const int lane = t & 63;
  const int l15 = lane & 15;
  const int lq = lane >> 4;
  const int wm = wave >> 2;  // 0..1 : M-half (32 rows)
  const int wn = wave & 3;   // 0..3 : N-quarter (64 cols)
  const int m_base = blockIdx.x * 64;

  // ---- A staging coords: thread t loads 16 consecutive fp32 of row (t>>3)
  const int srow = t >> 3;   // 0..63
  const int su = t & 7;      // float offset su*16
  const int gm = m_base + srow;
  const float* arow = (gm < E_NUM)
                          ? (node_embed + (size_t)gm * D_DIM + su * 16)
                          : (ori + (size_t)(gm - E_NUM) * D_DIM + su * 16);
  const int p0 = ((2 * su) ^ (srow & 7)) * 8;      // swizzled short offset, chunk 0
  const int p1 = ((2 * su + 1) ^ (srow & 7)) * 8;  // chunk 1
  const int wbase = srow * 128;

  // ---- B pointers: col = wn*64 + n*16 + l15, k-offset lq*8 within each kstep
  const short* bcol[4];
#pragma unroll
  for (int n = 0; n < 4; ++n)
    bcol[n] = W1T + (size_t)(wn * 64 + n * 16 + l15) * D_DIM + lq * 8;

  // ---- A fragment read: row rr = wm*32 + m*16 + l15, chunk kq = ks*4+lq at kq^(l15&7)
  const int asw = l15 & 7;

  f32x4 acc[2][4];
#pragma unroll
  for (int m = 0; m < 2; ++m)
#pragma unroll
    for (int n = 0; n < 4; ++n) acc[m][n] = (f32x4){0.f, 0.f, 0.f, 0.f};

  // ---- prologue: stage tile 0 into buf 0
  {
    f32x4 a0 = *(const f32x4*)(arow + 0);
    f32x4 a1 = *(const f32x4*)(arow + 4);
    f32x4 a2 = *(const f32x4*)(arow + 8);
    f32x4 a3 = *(const f32x4*)(arow + 12);
    short8 c0, c1;
#pragma unroll
    for (int j = 0; j < 4; ++j) {
      c0[j] = f2bf(a0[j]); c0[j + 4] = f2bf(a1[j]);
      c1[j] = f2bf(a2[j]); c1[j + 4] = f2bf(a3[j]);
    }
    *(short8*)&Als[0][wbase + p0] = c0;
    *(short8*)&Als[0][wbase + p1] = c1;
  }
  __syncthreads();

  int cur = 0;
  for (int it = 0; it < G1_STAGES; ++it) {
    const int nxt = cur ^ 1;
    const bool pf = (it + 1 < G1_STAGES);
    f32x4 a0, a1, a2, a3;
    if (pf) {
      const float* ap = arow + (it + 1) * 128;
      a0 = *(const f32x4*)(ap + 0);
      a1 = *(const f32x4*)(ap + 4);
      a2 = *(const f32x4*)(ap + 8);
      a3 = *(const f32x4*)(ap + 12);
    }

    const int k0 = it * 128;
    const short* Ac = &Als[cur][0];
#pragma unroll
    for (int ks = 0; ks < 4; ++ks) {
      bf16x8 bfv[4];
#pragma unroll
      for (int n = 0; n < 4; ++n) bfv[n] = ld_frag(bcol[n] + k0 + ks * 32);
      bf16x8 af[2];
#pragma unroll
      for (int m = 0; m < 2; ++m)
        af[m] = ld_frag(Ac + (wm * 32 + m * 16 + l15) * 128 + (((ks * 4 + lq) ^ asw) * 8));
#pragma unroll
      for (int m = 0; m < 2; ++m)
#pragma unroll
        for (int n = 0; n < 4; ++n)
          acc[m][n] = __builtin_amdgcn_mfma_f32_16x16x32_bf16(af[m], bfv[n], acc[m][n], 0, 0, 0);
    }

    if (pf) {
      short8 c0, c1;
#pragma unroll
      for (int j = 0; j < 4; ++j) {
        c0[j] = f2bf(a0[j]); c0[j + 4] = f2bf(a1[j]);
        c1[j] = f2bf(a2[j]); c1[j + 4] = f2bf(a3[j]);
      }
      *(short8*)&Als[nxt][wbase + p0] = c0;
      *(short8*)&Als[nxt][wbase + p1] = c1;
    }
    __syncthreads();
    cur = nxt;
  }

  // ---- epilogue: bias + silu + gate -> bf16
#pragma unroll
  for (int n = 0; n < 4; ++n) {
    const int col = wn * 64 + n * 16 + l15;
    const float b1v = b1[col];
#pragma unroll
    for (int m = 0; m < 2; ++m) {
#pragma unroll
      for (int i = 0; i < 4; ++i) {
        const int row = wm * 32 + m * 16 + lq * 4 + i;
        const int gmr = m_base + row;
        const int e = (gmr < E_NUM) ? gmr : gmr - E_NUM;
        float v = acc[m][n][i] + b1v;
        v = silu_f(v) * x_edge_c[(size_t)e * H_DIM + col];
        hg[(size_t)gmr * H_DIM + col] = f2bf(v);
      }
    }
  }
}

// -------------------- GEMM2: out[e] = silu(hg[e]@W2+b2) + silu(hg[e+E]@W2+b2) ------------
__launch_bounds__(256, 2)
__global__ void gemm2_kernel(const short* __restrict__ hg,
                             const short* __restrict__ W2T,
                             const float* __restrict__ b2,
                             float* __restrict__ out) {
  __shared__ short Als[2][64][40];
  __shared__ short Bls[128][40];

  const int t = threadIdx.x;
  const int wave = t >> 6;
  const int lane = t & 63;
  const int l15 = lane & 15;
  const int lq = lane >> 4;
  const int wr = wave >> 1;
  const int wc = wave & 1;

  const int d0 = blockIdx.x * 128;
  const int e0 = blockIdx.y * 64;

  const int srow = t >> 1;
  const int sk = (t & 1) * 16;
  const int half = srow >> 6;
  const int r = srow & 63;
  int ge = e0 + r;
  if (ge >= E_NUM) ge = E_NUM - 1;
  const short* a_src = hg + (size_t)(ge + half * E_NUM) * H_DIM + sk;
  const short* b_src = W2T + (size_t)(d0 + srow) * H_DIM + sk;

  f32x4 acc[2][2][4];
#pragma unroll
  for (int h = 0; h < 2; ++h)
#pragma unroll
    for (int m = 0; m < 2; ++m)
#pragma unroll
      for (int n = 0; n < 4; ++n) acc[h][m][n] = (f32x4){0.f, 0.f, 0.f, 0.f};

  for (int k0 = 0; k0 < H_DIM; k0 += 32) {
    *(short8*)&Als[half][r][sk] = *(const short8*)(a_src + k0);
    *(short8*)&Als[half][r][sk + 8] = *(const short8*)(a_src + k0 + 8);
    *(short8*)&Bls[srow][sk] = *(const short8*)(b_src + k0);
    *(short8*)&Bls[srow][sk + 8] = *(const short8*)(b_src + k0 + 8);
    __syncthreads();

    bf16x8 af[2][2], bfr[4];
#pragma unroll
    for (int h = 0; h < 2; ++h)
#pragma unroll
      for (int m = 0; m < 2; ++m)
        af[h][m] = ld_frag(&Als[h][wr * 32 + m * 16 + l15][lq * 8]);
#pragma unroll
    for (int n = 0; n < 4; ++n)
      bfr[n] = ld_frag(&Bls[wc * 64 + n * 16 + l15][lq * 8]);
#pragma unroll
    for (int h = 0; h < 2; ++h)
#pragma unroll
      for (int m = 0; m < 2; ++m)
#pragma unroll
        for (int n = 0; n < 4; ++n)
          acc[h][m][n] =
              __builtin_amdgcn_mfma_f32_16x16x32_bf16(af[h][m], bfr[n], acc[h][m][n], 0, 0, 0);
    __syncthreads();
  }

#pragma unroll
  for (int n = 0; n < 4; ++n) {
    const int cold = d0 + wc * 64 + n * 16 + l15;
    const float b2v = b2[cold];
#pragma unroll
    for (int m = 0; m < 2; ++m) {
#pragma unroll
      for (int i = 0; i < 4; ++i) {
        const int e = e0 + wr * 32 + m * 16 + lq * 4 + i;
        if (e < E_NUM) {
          float v0 = silu_f(acc[0][m][n][i] + b2v);
          float v1 = silu_f(acc[1][m][n][i] + b2v);
          out[(size_t)e * D_DIM + cold] = v0 + v1;
        }
      }
    }
  }
}

extern "C" void kernel_launch(void* const* d_in, const int* in_sizes, int n_in,
                              void* d_out, int out_size, void* d_ws, size_t ws_size,
                              hipStream_t stream) {
  const float* node_embed = (const float*)d_in[0];
  const float* x_edge_c = (const float*)d_in[1];
  const float* ori = (const float*)d_in[2];
  const float* W1 = (const float*)d_in[3];
  const float* b1 = (const float*)d_in[4];
  const float* W2 = (const float*)d_in[5];
  const float* b2 = (const float*)d_in[6];
  float* out_p = (float*)d_out;

  char* ws = (char*)d_ws;
  short* W1T = (short*)ws;
  short* W2T = (short*)(ws + 3211264);
  short* hg = (short*)(ws + 2 * 3211264);

  transpose_cvt<<<dim3(H_DIM / 32, D_DIM / 32), 256, 0, stream>>>(W1, W1T, D_DIM, H_DIM);
  transpose_cvt<<<dim3(D_DIM / 32, H_DIM / 32), 256, 0, stream>>>(W2, W2T, H_DIM, D_DIM);

  gemm1_kernel<<<dim3(M1 / 64), 512, 0, stream>>>(node_embed, ori, x_edge_c, W1T, b1, hg);

  gemm2_kernel<<<dim3(D_DIM / 128, (E_NUM + 63) / 64), 256, 0, stream>>>(hg, W2T, b2, out_p);
}

// Round 4
// 512.886 us; speedup vs baseline: 1.3250x; 1.3250x over previous
//
#include <hip/hip_runtime.h>

#define E_NUM 12000
#define D_DIM 6272
#define H_DIM 256
#define M1 (2 * E_NUM)  // 24000

typedef __attribute__((ext_vector_type(8))) short short8;
typedef __attribute__((ext_vector_type(8))) __bf16 bf16x8;
typedef __attribute__((ext_vector_type(4))) float f32x4;

__device__ __forceinline__ short f2bf(float f) {
  union { float f; unsigned u; } v; v.f = f;
  unsigned r = (v.u + 0x7FFFu + ((v.u >> 16) & 1u)) >> 16;
  return (short)r;
}

__device__ __forceinline__ float silu_f(float x) {
  return x / (1.0f + __expf(-x));
}

__device__ __forceinline__ bf16x8 ld_frag(const short* p) {
  return __builtin_bit_cast(bf16x8, *(const short8*)p);
}

// -------------------- transpose + fp32->bf16 convert --------------------
__global__ void transpose_cvt(const float* __restrict__ src, short* __restrict__ dst,
                              int R, int C) {
  __shared__ float tile[32][33];
  const int bx = blockIdx.x;
  const int by = blockIdx.y;
  const int t = threadIdx.x;
  const int ci = t & 31;
  const int r0 = t >> 5;
#pragma unroll
  for (int i = 0; i < 4; ++i) {
    int ri = r0 + i * 8;
    tile[ri][ci] = src[(size_t)(by * 32 + ri) * C + bx * 32 + ci];
  }
  __syncthreads();
#pragma unroll
  for (int i = 0; i < 4; ++i) {
    int orow = r0 + i * 8;
    dst[(size_t)(bx * 32 + orow) * R + by * 32 + ci] = f2bf(tile[ci][orow]);
  }
}

// ---------------- GEMM1 v4: BM=32, BK=128, depth-2 A prefetch, 3-buf LDS ----------------
// 256 threads = 4 waves; wave wn owns 64 output cols, all 32 rows.
// Invariant at top of stage it: buf[it%3] holds tile it; pA* hold loads of tile it+1.
#define G1_ST 49
__launch_bounds__(256, 3)
__global__ void gemm1_kernel(const float* __restrict__ node_embed,
                             const float* __restrict__ ori,
                             const float* __restrict__ x_edge_c,
                             const short* __restrict__ W1T,
                             const float* __restrict__ b1,
                             short* __restrict__ hg) {
  // A tile: 32 rows x 128 shorts, chunk c of row r stored at chunk c ^ (r&7)
  __shared__ __align__(16) short Als[3][32 * 128];  // 24 KB

  const int t = threadIdx.x;
  const int wn = t >> 6;     // wave 0..3 -> 64-col quarter
  const int lane = t & 63;
  const int l15 = lane & 15;
  const int lq = lane >> 4;
  const int m_base = blockIdx.x * 32;

  // A staging: thread t loads 16 fp32 of row (t>>3) at float-offset (t&7)*16
  const int srow = t >> 3;
  const int su = t & 7;
  const int gm = m_base + srow;
  const float* arow = (gm < E_NUM)
                          ? (node_embed + (size_t)gm * D_DIM + su * 16)
                          : (ori + (size_t)(gm - E_NUM) * D_DIM + su * 16);
  const int p0 = ((2 * su) ^ (srow & 7)) * 8;
  const int p1 = ((2 * su + 1) ^ (srow & 7)) * 8;
  const int wbase = srow * 128;

  // B column pointers (L2-resident W1T)
  const short* bp0 = W1T + (size_t)(wn * 64 + 0 * 16 + l15) * D_DIM + lq * 8;
  const short* bp1 = W1T + (size_t)(wn * 64 + 1 * 16 + l15) * D_DIM + lq * 8;
  const short* bp2 = W1T + (size_t)(wn * 64 + 2 * 16 + l15) * D_DIM + lq * 8;
  const short* bp3 = W1T + (size_t)(wn * 64 + 3 * 16 + l15) * D_DIM + lq * 8;

  const int asw = l15 & 7;

  f32x4 acc[2][4];
#pragma unroll
  for (int m = 0; m < 2; ++m)
#pragma unroll
    for (int n = 0; n < 4; ++n) acc[m][n] = (f32x4){0.f, 0.f, 0.f, 0.f};

  f32x4 pA0, pA1, pA2, pA3;
  // ---- prologue: tile0 -> buf0 ; tile1 -> pA regs
  {
    f32x4 t0 = *(const f32x4*)(arow + 0);
    f32x4 t1 = *(const f32x4*)(arow + 4);
    f32x4 t2 = *(const f32x4*)(arow + 8);
    f32x4 t3 = *(const f32x4*)(arow + 12);
    pA0 = *(const f32x4*)(arow + 128);
    pA1 = *(const f32x4*)(arow + 132);
    pA2 = *(const f32x4*)(arow + 136);
    pA3 = *(const f32x4*)(arow + 140);
    short8 c0, c1;
#pragma unroll
    for (int j = 0; j < 4; ++j) {
      c0[j] = f2bf(t0[j]); c0[j + 4] = f2bf(t1[j]);
      c1[j] = f2bf(t2[j]); c1[j + 4] = f2bf(t3[j]);
    }
    *(short8*)&Als[0][wbase + p0] = c0;
    *(short8*)&Als[0][wbase + p1] = c1;
  }
  __syncthreads();

  int cur = 0;
  for (int it = 0; it < G1_ST; ++it) {
    const int nxt = (cur == 2) ? 0 : cur + 1;
    // 1) issue loads for tile it+2
    f32x4 nA0, nA1, nA2, nA3;
    if (it < G1_ST - 2) {
      const float* ap = arow + (size_t)(it + 2) * 128;
      nA0 = *(const f32x4*)(ap + 0);
      nA1 = *(const f32x4*)(ap + 4);
      nA2 = *(const f32x4*)(ap + 8);
      nA3 = *(const f32x4*)(ap + 12);
    }
    // 2) cvt + write tile it+1 (loads issued a full stage ago -> no stall)
    if (it < G1_ST - 1) {
      short8 c0, c1;
#pragma unroll
      for (int j = 0; j < 4; ++j) {
        c0[j] = f2bf(pA0[j]); c0[j + 4] = f2bf(pA1[j]);
        c1[j] = f2bf(pA2[j]); c1[j + 4] = f2bf(pA3[j]);
      }
      *(short8*)&Als[nxt][wbase + p0] = c0;
      *(short8*)&Als[nxt][wbase + p1] = c1;
    }
    // 3) compute tile it from buf[cur]; B with 1-kstep lookahead regs
    {
      const short* Ac = &Als[cur][0];
      const size_t k0 = (size_t)it * 128;
      bf16x8 b0 = ld_frag(bp0 + k0);
      bf16x8 b1v = ld_frag(bp1 + k0);
      bf16x8 b2v = ld_frag(bp2 + k0);
      bf16x8 b3v = ld_frag(bp3 + k0);
#pragma unroll
      for (int ks = 0; ks < 4; ++ks) {
        bf16x8 x0, x1, x2, x3;
        if (ks < 3) {
          const size_t ko = k0 + (ks + 1) * 32;
          x0 = ld_frag(bp0 + ko);
          x1 = ld_frag(bp1 + ko);
          x2 = ld_frag(bp2 + ko);
          x3 = ld_frag(bp3 + ko);
        }
        bf16x8 af0 = ld_frag(Ac + (0 * 16 + l15) * 128 + (((ks * 4 + lq) ^ asw) * 8));
        bf16x8 af1 = ld_frag(Ac + (1 * 16 + l15) * 128 + (((ks * 4 + lq) ^ asw) * 8));
        acc[0][0] = __builtin_amdgcn_mfma_f32_16x16x32_bf16(af0, b0, acc[0][0], 0, 0, 0);
        acc[1][0] = __builtin_amdgcn_mfma_f32_16x16x32_bf16(af1, b0, acc[1][0], 0, 0, 0);
        acc[0][1] = __builtin_amdgcn_mfma_f32_16x16x32_bf16(af0, b1v, acc[0][1], 0, 0, 0);
        acc[1][1] = __builtin_amdgcn_mfma_f32_16x16x32_bf16(af1, b1v, acc[1][1], 0, 0, 0);
        acc[0][2] = __builtin_amdgcn_mfma_f32_16x16x32_bf16(af0, b2v, acc[0][2], 0, 0, 0);
        acc[1][2] = __builtin_amdgcn_mfma_f32_16x16x32_bf16(af1, b2v, acc[1][2], 0, 0, 0);
        acc[0][3] = __builtin_amdgcn_mfma_f32_16x16x32_bf16(af0, b3v, acc[0][3], 0, 0, 0);
        acc[1][3] = __builtin_amdgcn_mfma_f32_16x16x32_bf16(af1, b3v, acc[1][3], 0, 0, 0);
        if (ks < 3) { b0 = x0; b1v = x1; b2v = x2; b3v = x3; }
      }
    }
    // 4) rotate prefetch regs
    pA0 = nA0; pA1 = nA1; pA2 = nA2; pA3 = nA3;
    __syncthreads();
    cur = nxt;
  }

  // ---- epilogue: bias + silu + gate -> bf16
#pragma unroll
  for (int n = 0; n < 4; ++n) {
    const int col = wn * 64 + n * 16 + l15;
    const float b1v = b1[col];
#pragma unroll
    for (int m = 0; m < 2; ++m) {
#pragma unroll
      for (int i = 0; i < 4; ++i) {
        const int row = m * 16 + lq * 4 + i;
        const int gmr = m_base + row;
        const int e = (gmr < E_NUM) ? gmr : gmr - E_NUM;
        float v = acc[m][n][i] + b1v;
        v = silu_f(v) * x_edge_c[(size_t)e * H_DIM + col];
        hg[(size_t)gmr * H_DIM + col] = f2bf(v);
      }
    }
  }
}

// ---------------- GEMM2 v2: 128e x 128d tile, 512 thr, dbuf reg-prefetch ----------------
// out[e] = silu(hg[e]@W2+b2) + silu(hg[e+E]@W2+b2)
__launch_bounds__(512, 4)
__global__ void gemm2_kernel(const short* __restrict__ hg,
                             const short* __restrict__ W2T,
                             const float* __restrict__ b2,
                             float* __restrict__ out) {
  __shared__ short Ah[2][256][40];  // [buf][half*128 + e_row][k] 40 KB
  __shared__ short Bl[2][128][40];  // [buf][d_col][k] 20 KB

  const int t = threadIdx.x;
  const int wave = t >> 6;
  const int lane = t & 63;
  const int l15 = lane & 15;
  const int lq = lane >> 4;
  const int we = wave >> 2;  // 0..1: e-half (64 rows)
  const int wd = wave & 3;   // 0..3: d-slice (32 cols)

  const int d0 = blockIdx.x * 128;
  const int e0 = blockIdx.y * 128;

  // A staging: sr = t>>1 (0..255), sk = (t&1)*16 (32B per thread)
  const int sr = t >> 1;
  const int ska = (t & 1) * 16;
  const int half = sr >> 7;
  const int r = sr & 127;
  int ge = e0 + r;
  if (ge >= E_NUM) ge = E_NUM - 1;
  const short* a_src = hg + (size_t)(ge + half * E_NUM) * H_DIM + ska;
  // B staging: br = t>>2 (0..127), bc = (t&3)*8 (16B per thread)
  const int br = t >> 2;
  const int bc = (t & 3) * 8;
  const short* b_src = W2T + (size_t)(d0 + br) * H_DIM + bc;

  f32x4 acc[2][4][2];
#pragma unroll
  for (int h = 0; h < 2; ++h)
#pragma unroll
    for (int m = 0; m < 4; ++m)
#pragma unroll
      for (int n = 0; n < 2; ++n) acc[h][m][n] = (f32x4){0.f, 0.f, 0.f, 0.f};

  // prologue: stage k=0 into buf 0
  {
    *(short8*)&Ah[0][sr][ska] = *(const short8*)(a_src);
    *(short8*)&Ah[0][sr][ska + 8] = *(const short8*)(a_src + 8);
    *(short8*)&Bl[0][br][bc] = *(const short8*)(b_src);
  }
  __syncthreads();

  int cur = 0;
#pragma unroll
  for (int kt = 0; kt < 8; ++kt) {
    const int nxt = cur ^ 1;
    short8 ra0, ra1, rb;
    if (kt < 7) {
      const int k0 = (kt + 1) * 32;
      ra0 = *(const short8*)(a_src + k0);
      ra1 = *(const short8*)(a_src + k0 + 8);
      rb = *(const short8*)(b_src + k0);
    }

    bf16x8 af[2][4], bfr[2];
#pragma unroll
    for (int h = 0; h < 2; ++h)
#pragma unroll
      for (int m = 0; m < 4; ++m)
        af[h][m] = ld_frag(&Ah[cur][h * 128 + we * 64 + m * 16 + l15][lq * 8]);
#pragma unroll
    for (int n = 0; n < 2; ++n)
      bfr[n] = ld_frag(&Bl[cur][wd * 32 + n * 16 + l15][lq * 8]);
#pragma unroll
    for (int h = 0; h < 2; ++h)
#pragma unroll
      for (int m = 0; m < 4; ++m)
#pragma unroll
        for (int n = 0; n < 2; ++n)
          acc[h][m][n] =
              __builtin_amdgcn_mfma_f32_16x16x32_bf16(af[h][m], bfr[n], acc[h][m][n], 0, 0, 0);

    if (kt < 7) {
      *(short8*)&Ah[nxt][sr][ska] = ra0;
      *(short8*)&Ah[nxt][sr][ska + 8] = ra1;
      *(short8*)&Bl[nxt][br][bc] = rb;
    }
    __syncthreads();
    cur = nxt;
  }

#pragma unroll
  for (int n = 0; n < 2; ++n) {
    const int cold = d0 + wd * 32 + n * 16 + l15;
    const float b2v = b2[cold];
#pragma unroll
    for (int m = 0; m < 4; ++m) {
#pragma unroll
      for (int i = 0; i < 4; ++i) {
        const int e = e0 + we * 64 + m * 16 + lq * 4 + i;
        if (e < E_NUM) {
          float v0 = silu_f(acc[0][m][n][i] + b2v);
          float v1 = silu_f(acc[1][m][n][i] + b2v);
          out[(size_t)e * D_DIM + cold] = v0 + v1;
        }
      }
    }
  }
}

extern "C" void kernel_launch(void* const* d_in, const int* in_sizes, int n_in,
                              void* d_out, int out_size, void* d_ws, size_t ws_size,
                              hipStream_t stream) {
  const float* node_embed = (const float*)d_in[0];
  const float* x_edge_c = (const float*)d_in[1];
  const float* ori = (const float*)d_in[2];
  const float* W1 = (const float*)d_in[3];
  const float* b1 = (const float*)d_in[4];
  const float* W2 = (const float*)d_in[5];
  const float* b2 = (const float*)d_in[6];
  float* out_p = (float*)d_out;

  char* ws = (char*)d_ws;
  short* W1T = (short*)ws;
  short* W2T = (short*)(ws + 3211264);
  short* hg = (short*)(ws + 2 * 3211264);

  transpose_cvt<<<dim3(H_DIM / 32, D_DIM / 32), 256, 0, stream>>>(W1, W1T, D_DIM, H_DIM);
  transpose_cvt<<<dim3(D_DIM / 32, H_DIM / 32), 256, 0, stream>>>(W2, W2T, H_DIM, D_DIM);

  gemm1_kernel<<<dim3(M1 / 32), 256, 0, stream>>>(node_embed, ori, x_edge_c, W1T, b1, hg);

  gemm2_kernel<<<dim3(D_DIM / 128, (E_NUM + 127) / 128), 512, 0, stream>>>(hg, W2T, b2, out_p);
}

// Round 5
// 490.713 us; speedup vs baseline: 1.3848x; 1.0452x over previous
//
#include <hip/hip_runtime.h>

#define E_NUM 12000
#define D_DIM 6272
#define H_DIM 256
#define M1 (2 * E_NUM)  // 24000

typedef __attribute__((ext_vector_type(4))) short short4v;
typedef __attribute__((ext_vector_type(8))) short short8;
typedef __attribute__((ext_vector_type(8))) __bf16 bf16x8;
typedef __attribute__((ext_vector_type(4))) float f32x4;

__device__ __forceinline__ short f2bf(float f) {
  union { float f; unsigned u; } v; v.f = f;
  unsigned r = (v.u + 0x7FFFu + ((v.u >> 16) & 1u)) >> 16;
  return (short)r;
}

__device__ __forceinline__ float silu_f(float x) {
  return x / (1.0f + __expf(-x));
}

__device__ __forceinline__ bf16x8 ld_frag(const short* p) {
  return __builtin_bit_cast(bf16x8, *(const short8*)p);
}

__device__ __forceinline__ void cvt_write8(short* dst, f32x4 v) {
  short4v s;
#pragma unroll
  for (int j = 0; j < 4; ++j) s[j] = f2bf(v[j]);
  *(short4v*)dst = s;
}

// ---------------- panel pack: src [R][C] fp32 -> dst[(R/32)*C + c][32] bf16 ----------------
// dst[((r32)*C + c)*32 + j] = bf(src[(r32*32+j)*C + c]).  grid = (C/32, R/32), 256 thr.
__global__ void pack_panel(const float* __restrict__ src, short* __restrict__ dst, int C) {
  __shared__ float tile[32][33];
  const int bx = blockIdx.x;  // col tile
  const int by = blockIdx.y;  // k tile
  const int t = threadIdx.x;
  const int ci = t & 31;
  const int r0 = t >> 5;
#pragma unroll
  for (int i = 0; i < 4; ++i) {
    int ri = r0 + i * 8;
    tile[ri][ci] = src[(size_t)(by * 32 + ri) * C + bx * 32 + ci];
  }
  __syncthreads();
#pragma unroll
  for (int i = 0; i < 4; ++i) {
    int orow = r0 + i * 8;  // col within tile
    dst[((size_t)by * C + bx * 32 + orow) * 32 + ci] = f2bf(tile[ci][orow]);
  }
}

// ---------------- GEMM1 v5: contiguous A loads, panel-B direct from L2 ----------------
// x = concat(node_embed, ori) [24000][6272] fp32; P1 panel [196][256][32] bf16.
// Output hg in PANEL layout: hgp[(p*24000 + row)*32 + c] = hg[row][p*32+c], p=0..7.
// 256 thr = 4 waves; BM=32, BK=128 (4 ksteps/stage), 49 stages, triple-buffer LDS.
#define G1_ST 49
__launch_bounds__(256, 3)
__global__ void gemm1_kernel(const float* __restrict__ node_embed,
                             const float* __restrict__ ori,
                             const float* __restrict__ x_edge_c,
                             const short* __restrict__ P1,
                             const float* __restrict__ b1,
                             short* __restrict__ hgp) {
  // A tile: 32 rows x 128 shorts (256B/row, 16 chunks of 16B); chunk g of row r at g^(r&7)
  __shared__ __align__(16) short Als[3][32 * 128];  // 24 KB

  const int t = threadIdx.x;
  const int wn = t >> 6;
  const int lane = t & 63;
  const int l15 = lane & 15;
  const int lq = lane >> 4;
  const int bx = blockIdx.x;
  const int m_base = bx * 32;
  const bool is_node = (bx < (E_NUM / 32));

  const float* xbase = is_node ? (node_embed + (size_t)m_base * D_DIM)
                               : (ori + (size_t)(m_base - E_NUM) * D_DIM);
  // A staging: round j (0..3): row = j*8 + (t>>5), 16B unit ci = t&31 -> CONTIGUOUS 512B/row
  const int ci = t & 31;
  const int r0 = t >> 5;
  const float* asrc = xbase + (size_t)r0 * D_DIM + ci * 4;  // +j*8*D_DIM +it*128
  // LDS write: 8B at row*128 + ((ci>>1)^row&7)*8 + (ci&1)*4 ; row&7 == r0 for all rounds
  const int wbase = r0 * 128 + (((ci >> 1) ^ r0) * 8) + (ci & 1) * 4;  // +j*1024

  // B: fully-coalesced 1KB fragment loads from panel
  const short* bptr = P1 + (size_t)(wn * 64 + l15) * 32 + lq * 8;
  const int asw = l15 & 7;

  f32x4 acc[2][4];
#pragma unroll
  for (int m = 0; m < 2; ++m)
#pragma unroll
    for (int n = 0; n < 4; ++n) acc[m][n] = (f32x4){0.f, 0.f, 0.f, 0.f};

  f32x4 pF0, pF1, pF2, pF3;
  {
    f32x4 c0 = *(const f32x4*)(asrc + (size_t)0 * 8 * D_DIM);
    f32x4 c1 = *(const f32x4*)(asrc + (size_t)1 * 8 * D_DIM);
    f32x4 c2 = *(const f32x4*)(asrc + (size_t)2 * 8 * D_DIM);
    f32x4 c3 = *(const f32x4*)(asrc + (size_t)3 * 8 * D_DIM);
    pF0 = *(const f32x4*)(asrc + (size_t)0 * 8 * D_DIM + 128);
    pF1 = *(const f32x4*)(asrc + (size_t)1 * 8 * D_DIM + 128);
    pF2 = *(const f32x4*)(asrc + (size_t)2 * 8 * D_DIM + 128);
    pF3 = *(const f32x4*)(asrc + (size_t)3 * 8 * D_DIM + 128);
    cvt_write8(&Als[0][wbase + 0 * 1024], c0);
    cvt_write8(&Als[0][wbase + 1 * 1024], c1);
    cvt_write8(&Als[0][wbase + 2 * 1024], c2);
    cvt_write8(&Als[0][wbase + 3 * 1024], c3);
  }
  __syncthreads();

  int cur = 0;
  for (int it = 0; it < G1_ST; ++it) {
    const int nxt = (cur == 2) ? 0 : cur + 1;
    // (1) A loads for tile it+2
    f32x4 nF0, nF1, nF2, nF3;
    if (it < G1_ST - 2) {
      const float* ap = asrc + (size_t)(it + 2) * 128;
      nF0 = *(const f32x4*)(ap + (size_t)0 * 8 * D_DIM);
      nF1 = *(const f32x4*)(ap + (size_t)1 * 8 * D_DIM);
      nF2 = *(const f32x4*)(ap + (size_t)2 * 8 * D_DIM);
      nF3 = *(const f32x4*)(ap + (size_t)3 * 8 * D_DIM);
    }
    // (2) all 16 B fragments for this stage (each: 16 rows x 64B = 1KB contiguous)
    bf16x8 bq[4][4];
    {
      const short* bs = bptr + (size_t)it * 32768;
#pragma unroll
      for (int ks = 0; ks < 4; ++ks)
#pragma unroll
        for (int n = 0; n < 4; ++n)
          bq[ks][n] = ld_frag(bs + ks * 8192 + n * 512);
    }
    // (3) cvt + write tile it+1 (loads completed a stage ago)
    if (it < G1_ST - 1) {
      short* wd = &Als[nxt][0];
      cvt_write8(wd + wbase + 0 * 1024, pF0);
      cvt_write8(wd + wbase + 1 * 1024, pF1);
      cvt_write8(wd + wbase + 2 * 1024, pF2);
      cvt_write8(wd + wbase + 3 * 1024, pF3);
    }
    // (4) compute
    const short* Ac = &Als[cur][0];
#pragma unroll
    for (int ks = 0; ks < 4; ++ks) {
      bf16x8 af0 = ld_frag(Ac + (0 * 16 + l15) * 128 + (((ks * 4 + lq) ^ asw) * 8));
      bf16x8 af1 = ld_frag(Ac + (1 * 16 + l15) * 128 + (((ks * 4 + lq) ^ asw) * 8));
#pragma unroll
      for (int n = 0; n < 4; ++n) {
        acc[0][n] = __builtin_amdgcn_mfma_f32_16x16x32_bf16(af0, bq[ks][n], acc[0][n], 0, 0, 0);
        acc[1][n] = __builtin_amdgcn_mfma_f32_16x16x32_bf16(af1, bq[ks][n], acc[1][n], 0, 0, 0);
      }
    }
    pF0 = nF0; pF1 = nF1; pF2 = nF2; pF3 = nF3;
    __syncthreads();
    cur = nxt;
  }

  // ---- epilogue: bias + silu + gate -> hg panel layout
#pragma unroll
  for (int n = 0; n < 4; ++n) {
    const int col = wn * 64 + n * 16 + l15;
    const float b1v = b1[col];
    const int panel = wn * 2 + (n >> 1);
    const int cin = (n & 1) * 16 + l15;
#pragma unroll
    for (int m = 0; m < 2; ++m) {
#pragma unroll
      for (int i = 0; i < 4; ++i) {
        const int row = m * 16 + lq * 4 + i;
        const int gmr = m_base + row;
        const int e = is_node ? gmr : gmr - E_NUM;
        float v = acc[m][n][i] + b1v;
        v = silu_f(v) * x_edge_c[(size_t)e * H_DIM + col];
        hgp[((size_t)panel * M1 + gmr) * 32 + cin] = f2bf(v);
      }
    }
  }
}

// ---------------- GEMM2 v3: all-coalesced panels, BM=64e, BN=128d, 256 thr ----------------
// out[e] = silu(hg[e]@W2+b2) + silu(hg[e+E]@W2+b2); hg from panel hgp, W2 from panel P2.
__launch_bounds__(256, 4)
__global__ void gemm2_kernel(const short* __restrict__ hgp,
                             const short* __restrict__ P2,
                             const float* __restrict__ b2,
                             float* __restrict__ out) {
  __shared__ __align__(16) short Ah[2][128 * 32];  // 2 x 8KB: rows 0..63 = e-half, 64..127 = e+E

  const int t = threadIdx.x;
  const int wd = t >> 6;  // wave -> 32 d-cols
  const int lane = t & 63;
  const int l15 = lane & 15;
  const int lq = lane >> 4;
  const int d0 = blockIdx.x * 128;
  const int e0 = blockIdx.y * 64;

  // A staging: thread t stages 16B: row-in-half = t>>2, chunk = t&3 (contiguous 4KB/round)
  const int ar = t >> 2;
  const int ac = t & 3;
  int ge = e0 + ar;
  if (ge >= E_NUM) ge = E_NUM - 1;
  const short* a_src0 = hgp + (size_t)ge * 32 + ac * 8;            // +k*M1*32
  const short* a_src1 = hgp + (size_t)(ge + E_NUM) * 32 + ac * 8;  // +k*M1*32
  const int aw0 = ar * 32 + ((ac ^ (ar & 3)) * 8);
  const int aw1 = (64 + ar) * 32 + ((ac ^ (ar & 3)) * 8);
  // B: 1KB coalesced fragment loads from W2 panel
  const short* b_src0 = P2 + (size_t)(d0 + wd * 32 + l15) * 32 + lq * 8;
  const short* b_src1 = P2 + (size_t)(d0 + wd * 32 + 16 + l15) * 32 + lq * 8;

  f32x4 acc[2][4][2];
#pragma unroll
  for (int h = 0; h < 2; ++h)
#pragma unroll
    for (int m = 0; m < 4; ++m)
#pragma unroll
      for (int n = 0; n < 2; ++n) acc[h][m][n] = (f32x4){0.f, 0.f, 0.f, 0.f};

  *(short8*)&Ah[0][aw0] = *(const short8*)(a_src0);
  *(short8*)&Ah[0][aw1] = *(const short8*)(a_src1);
  bf16x8 bq0 = ld_frag(b_src0);
  bf16x8 bq1 = ld_frag(b_src1);
  __syncthreads();

  int cur = 0;
#pragma unroll
  for (int kt = 0; kt < 8; ++kt) {
    const int nxt = cur ^ 1;
    short8 rA0, rA1;
    bf16x8 nb0, nb1;
    if (kt < 7) {
      const size_t ka = (size_t)(kt + 1) * (M1 * 32);
      const size_t kb = (size_t)(kt + 1) * (D_DIM * 32);
      rA0 = *(const short8*)(a_src0 + ka);
      rA1 = *(const short8*)(a_src1 + ka);
      nb0 = ld_frag(b_src0 + kb);
      nb1 = ld_frag(b_src1 + kb);
    }
#pragma unroll
    for (int h = 0; h < 2; ++h) {
#pragma unroll
      for (int m = 0; m < 4; ++m) {
        const int row = h * 64 + m * 16 + l15;
        bf16x8 af = ld_frag(&Ah[cur][row * 32 + ((lq ^ (l15 & 3)) * 8)]);
        acc[h][m][0] = __builtin_amdgcn_mfma_f32_16x16x32_bf16(af, bq0, acc[h][m][0], 0, 0, 0);
        acc[h][m][1] = __builtin_amdgcn_mfma_f32_16x16x32_bf16(af, bq1, acc[h][m][1], 0, 0, 0);
      }
    }
    if (kt < 7) {
      *(short8*)&Ah[nxt][aw0] = rA0;
      *(short8*)&Ah[nxt][aw1] = rA1;
      bq0 = nb0; bq1 = nb1;
    }
    __syncthreads();
    cur = nxt;
  }

#pragma unroll
  for (int n = 0; n < 2; ++n) {
    const int cold = d0 + wd * 32 + n * 16 + l15;
    const float b2v = b2[cold];
#pragma unroll
    for (int m = 0; m < 4; ++m) {
#pragma unroll
      for (int i = 0; i < 4; ++i) {
        const int e = e0 + m * 16 + lq * 4 + i;
        if (e < E_NUM) {
          float v0 = silu_f(acc[0][m][n][i] + b2v);
          float v1 = silu_f(acc[1][m][n][i] + b2v);
          out[(size_t)e * D_DIM + cold] = v0 + v1;
        }
      }
    }
  }
}

extern "C" void kernel_launch(void* const* d_in, const int* in_sizes, int n_in,
                              void* d_out, int out_size, void* d_ws, size_t ws_size,
                              hipStream_t stream) {
  const float* node_embed = (const float*)d_in[0];
  const float* x_edge_c = (const float*)d_in[1];
  const float* ori = (const float*)d_in[2];
  const float* W1 = (const float*)d_in[3];
  const float* b1 = (const float*)d_in[4];
  const float* W2 = (const float*)d_in[5];
  const float* b2 = (const float*)d_in[6];
  float* out_p = (float*)d_out;

  char* ws = (char*)d_ws;
  short* P1 = (short*)ws;                    // [196][256][32] bf16 = 3,211,264 B
  short* P2 = (short*)(ws + 3211264);        // [8][6272][32] bf16 = 3,211,264 B
  short* hgp = (short*)(ws + 2 * 3211264);   // [8][24000][32] bf16 = 12,288,000 B

  // W1 [6272][256] -> P1 ; W2 [256][6272] -> P2
  pack_panel<<<dim3(H_DIM / 32, D_DIM / 32), 256, 0, stream>>>(W1, P1, H_DIM);
  pack_panel<<<dim3(D_DIM / 32, H_DIM / 32), 256, 0, stream>>>(W2, P2, D_DIM);

  gemm1_kernel<<<dim3(M1 / 32), 256, 0, stream>>>(node_embed, ori, x_edge_c, P1, b1, hgp);

  gemm2_kernel<<<dim3(D_DIM / 128, (E_NUM + 63) / 64), 256, 0, stream>>>(hgp, P2, b2, out_p);
}